// Round 8
// baseline (1428.039 us; speedup 1.0000x reference)
//
#include <hip/hip_runtime.h>
#include <math.h>

// ---------------------------------------------------------------------------
// R-GCN (basis decomposition, B=2), 2 layers.
//   C[n, 0:192] = x[n,:] @ [loop_w | basis0 | basis1]   (dense, MFMA bf16x3)
//   self = C[:,0:64]+bias ;  hb2[n][j] = (C[n,64+j], C[n,128+j])  (float2)
//   out[n] = act(self[n] + sum_{e: dst=n} c0*hb2[src][j].x + c1*hb2[src][j].y)
//
// Dense via matrix cores with fp32 emulation: x = xh + xl, w = wh + wl
// (bf16 hi/lo, RNE); C = xh*wh + xh*wl + xl*wh  (xl*wl ~ 2^-18, dropped).
//
// Edge aggregation: edges grouped by 128-node DST BUCKET (not per node - no
// random 4B scatter, lines fill before eviction). One block per bucket with
// a 32KB LDS accumulator; waves shfl-broadcast packed records and gather
// hb2[src] rows with 4-deep MLP; ds_add_f32 accumulation (conflict-free).
// rec = dl(7)<<23 | src(17)<<6 | et(6).
// ---------------------------------------------------------------------------

typedef short          short8 __attribute__((ext_vector_type(8)));
typedef float          f32x4  __attribute__((ext_vector_type(4)));
typedef unsigned short u16;

static __device__ __forceinline__ u16 bf16_rne(float x) {
    unsigned u = __float_as_uint(x);
    return (u16)((u + 0x7fffu + ((u >> 16) & 1u)) >> 16);
}
static __device__ __forceinline__ float bf16_f32(u16 h) {
    return __uint_as_float(((unsigned)h) << 16);
}

// ---------------- W pre-convert: Wt[192][K] bf16 hi/lo (transposed) --------
__global__ __launch_bounds__(256) void wconv(
    const float* __restrict__ loopw1, const float* __restrict__ basis1,
    const float* __restrict__ loopw2, const float* __restrict__ basis2,
    u16* __restrict__ wt1h, u16* __restrict__ wt1l,
    u16* __restrict__ wt2h, u16* __restrict__ wt2l)
{
    const int tid = blockIdx.x * 256 + threadIdx.x;
    if (tid < 192 * 128) {                       // layer 1, K=128
        const int j = tid >> 7, k = tid & 127;
        const float w = (j < 64)
            ? loopw1[k * 64 + j]
            : basis1[(size_t)((j - 64) >> 6) * (128 * 64) + k * 64 + ((j - 64) & 63)];
        const u16 h = bf16_rne(w);
        wt1h[tid] = h;
        wt1l[tid] = bf16_rne(w - bf16_f32(h));
    }
    if (tid < 192 * 64) {                        // layer 2, K=64
        const int j = tid >> 6, k = tid & 63;
        const float w = (j < 64)
            ? loopw2[k * 64 + j]
            : basis2[(size_t)((j - 64) >> 6) * (64 * 64) + k * 64 + ((j - 64) & 63)];
        const u16 h = bf16_rne(w);
        wt2h[tid] = h;
        wt2l[tid] = bf16_rne(w - bf16_f32(h));
    }
}

// ---------------- dense: 128 nodes/block, 8 waves, W in LDS ----------------
template<int K>
__global__ __launch_bounds__(512, 2) void rgcn_dense_mfma(
    const float* __restrict__ x,     // [N][K] f32
    const u16* __restrict__ wth,     // [192][K] bf16 hi (transposed)
    const u16* __restrict__ wtl,     // [192][K] bf16 lo
    const float* __restrict__ bias,  // [64]
    float* __restrict__ self,        // [N][64]  = x@loopw + bias
    float2* __restrict__ hb2,        // [N][64]  = (x@basis0, x@basis1) pairs
    int nNodes)
{
    constexpr int KC  = K / 32;          // mfma K-steps
    constexpr int GW  = K / 8;           // 16B granules per (col,split)
    constexpr int GMW = GW - 1;          // granule XOR mask
    __shared__ u16 wlds[96 * 2 * K];     // one 96-col half of W (hi+lo)

    const int n0   = blockIdx.x * 128;
    const int lane = threadIdx.x & 63;
    const int w    = threadIdx.x >> 6;   // 0..7
    const int rl   = lane & 15;          // A row / B col / D col
    const int kb   = lane >> 4;          // k-block

    // ---- A fragments: global -> reg, convert to bf16 hi/lo ----
    const int row = n0 + w * 16 + rl;
    short8 Ah[KC], Al[KC];
    #pragma unroll
    for (int kc = 0; kc < KC; ++kc) {
        float v[8];
        if (row < nNodes) {
            const float* xp = x + (size_t)row * K + kc * 32 + kb * 8;
            const float4 a = *reinterpret_cast<const float4*>(xp);
            const float4 b = *reinterpret_cast<const float4*>(xp + 4);
            v[0] = a.x; v[1] = a.y; v[2] = a.z; v[3] = a.w;
            v[4] = b.x; v[5] = b.y; v[6] = b.z; v[7] = b.w;
        } else {
            #pragma unroll
            for (int i = 0; i < 8; ++i) v[i] = 0.f;
        }
        #pragma unroll
        for (int i = 0; i < 8; ++i) {
            const u16 h = bf16_rne(v[i]);
            Ah[kc][i] = (short)h;
            Al[kc][i] = (short)bf16_rne(v[i] - bf16_f32(h));
        }
    }

    f32x4 acc[12];
    #pragma unroll
    for (int j = 0; j < 12; ++j) acc[j] = (f32x4){0.f, 0.f, 0.f, 0.f};

    #pragma unroll
    for (int hf = 0; hf < 2; ++hf) {
        if (hf) __syncthreads();         // protect LDS before overwrite
        // ---- stage 96 cols of W (hi+lo) into LDS, XOR-swizzled ----
        for (int gi = threadIdx.x; gi < 96 * 2 * GW; gi += 512) {
            const int ch = gi / (2 * GW);
            const int r  = gi - ch * 2 * GW;
            const int s  = r / GW;
            const int g  = r - s * GW;
            const u16* sp = (s == 0 ? wth : wtl)
                          + (size_t)(hf * 96 + ch) * K + g * 8;
            const short8 vv = *reinterpret_cast<const short8*>(sp);
            *reinterpret_cast<short8*>(
                &wlds[((ch * 2 + s) * GW + (g ^ (ch & GMW))) * 8]) = vv;
        }
        __syncthreads();

        #pragma unroll
        for (int j16h = 0; j16h < 6; ++j16h) {
            const int ch = j16h * 16 + rl;
            const u16* bbase = &wlds[(ch * 2) * GW * 8];
            #pragma unroll
            for (int kc = 0; kc < KC; ++kc) {
                const int gp = (kc * 4 + kb) ^ (ch & GMW);
                const short8 Bh =
                    *reinterpret_cast<const short8*>(bbase + gp * 8);
                const short8 Bl =
                    *reinterpret_cast<const short8*>(bbase + (GW + gp) * 8);
                f32x4 a = acc[hf * 6 + j16h];
                a = __builtin_amdgcn_mfma_f32_16x16x32_bf16(Ah[kc], Bh, a, 0, 0, 0);
                a = __builtin_amdgcn_mfma_f32_16x16x32_bf16(Ah[kc], Bl, a, 0, 0, 0);
                a = __builtin_amdgcn_mfma_f32_16x16x32_bf16(Al[kc], Bh, a, 0, 0, 0);
                acc[hf * 6 + j16h] = a;
            }
        }
    }

    // ---- epilogue: D[(kb*4+r)][rl] ----
    const int rowbase = n0 + w * 16 + kb * 4;
    #pragma unroll
    for (int j16 = 0; j16 < 4; ++j16) {          // cols 0..63 -> self + bias
        const float bj = bias[j16 * 16 + rl];
        #pragma unroll
        for (int r = 0; r < 4; ++r) {
            const int rr = rowbase + r;
            if (rr < nNodes)
                self[(size_t)rr * 64 + j16 * 16 + rl] = acc[j16][r] + bj;
        }
    }
    #pragma unroll
    for (int j16 = 4; j16 < 8; ++j16) {          // (basis0, basis1) pairs
        #pragma unroll
        for (int r = 0; r < 4; ++r) {
            const int rr = rowbase + r;
            if (rr < nNodes)
                hb2[(size_t)rr * 64 + (j16 - 4) * 16 + rl] =
                    make_float2(acc[j16][r], acc[j16 + 4][r]);
        }
    }
}

// ---------------- bucket build (3 tiny kernels) ----------------------------
__global__ __launch_bounds__(256) void bkt_hist(
    const int* __restrict__ dst, int* __restrict__ hist, int nE)
{
    const int e = blockIdx.x * 256 + threadIdx.x;
    if (e < nE) atomicAdd(&hist[dst[e] >> 7], 1);
}

__global__ __launch_bounds__(1024) void bkt_scan(
    const int* __restrict__ hist, int* __restrict__ boff,
    int* __restrict__ cursor, int nB, int nE)
{
    __shared__ int sm[1024];
    const int t = threadIdx.x;
    const int v = (t < nB) ? hist[t] : 0;
    sm[t] = v; __syncthreads();
    for (int off = 1; off < 1024; off <<= 1) {
        const int u = (t >= off) ? sm[t - off] : 0;
        __syncthreads();
        sm[t] += u;
        __syncthreads();
    }
    if (t < nB) {
        const int ex = sm[t] - v;      // exclusive
        boff[t] = ex;
        cursor[t] = ex;
    }
    if (t == 0) boff[nB] = nE;
}

// rec = dl(7)<<23 | src(17)<<6 | et(6); writes cluster inside bucket regions
__global__ __launch_bounds__(256) void bkt_scatter(
    const int* __restrict__ src, const int* __restrict__ dst,
    const int* __restrict__ et, int* __restrict__ cursor,
    unsigned* __restrict__ rec, int nE)
{
    const int e = blockIdx.x * 256 + threadIdx.x;
    if (e < nE) {
        const int d = dst[e];
        const int p = atomicAdd(&cursor[d >> 7], 1);
        rec[p] = ((unsigned)(d & 127) << 23)
               | ((unsigned)src[e] << 6)
               | (unsigned)et[e];
    }
}

// ---------------- edge aggregation: one block per 128-node bucket ----------
template<int ACT>   // 0 = tanh, 1 = relu
__global__ __launch_bounds__(512) void rgcn_agg(
    const float2* __restrict__ hb2,     // [N][64] float2 (b0,b1)
    const float* __restrict__ comp,     // [R][2]
    const int* __restrict__ boff,       // [nB+1]
    const unsigned* __restrict__ rec,   // [E] bucket-grouped
    float* __restrict__ io,             // in: self+bias, out: act(self+agg)
    int nNodes)
{
    __shared__ float acc[128 * 64];     // 32 KB
    const int b    = blockIdx.x;
    const int n0   = b << 7;
    const int lane = threadIdx.x & 63;
    const int w    = threadIdx.x >> 6;  // 0..7

    {   // zero-init
        float4* a4 = reinterpret_cast<float4*>(acc);
        for (int i = threadIdx.x; i < 128 * 16; i += 512)
            a4[i] = make_float4(0.f, 0.f, 0.f, 0.f);
    }
    __syncthreads();

    const int beg = boff[b], end = boff[b + 1];
    const float2* __restrict__ comp2 = reinterpret_cast<const float2*>(comp);

    for (int base = beg + (w << 6); base < end; base += (8 << 6)) {
        const int cnt = min(64, end - base);
        const unsigned r = (lane < cnt) ? rec[base + lane] : 0u;
        int i = 0;
        for (; i + 4 <= cnt; i += 4) {
            const unsigned rA = __shfl(r, i),     rB = __shfl(r, i + 1);
            const unsigned rC = __shfl(r, i + 2), rD = __shfl(r, i + 3);
            const float2 vA = hb2[(size_t)((rA >> 6) & 0x1FFFFu) * 64 + lane];
            const float2 vB = hb2[(size_t)((rB >> 6) & 0x1FFFFu) * 64 + lane];
            const float2 vC = hb2[(size_t)((rC >> 6) & 0x1FFFFu) * 64 + lane];
            const float2 vD = hb2[(size_t)((rD >> 6) & 0x1FFFFu) * 64 + lane];
            const float2 cA = comp2[rA & 63u], cB = comp2[rB & 63u];
            const float2 cC = comp2[rC & 63u], cD = comp2[rD & 63u];
            atomicAdd(&acc[((rA >> 23) << 6) + lane], cA.x * vA.x + cA.y * vA.y);
            atomicAdd(&acc[((rB >> 23) << 6) + lane], cB.x * vB.x + cB.y * vB.y);
            atomicAdd(&acc[((rC >> 23) << 6) + lane], cC.x * vC.x + cC.y * vC.y);
            atomicAdd(&acc[((rD >> 23) << 6) + lane], cD.x * vD.x + cD.y * vD.y);
        }
        for (; i < cnt; ++i) {
            const unsigned rA = __shfl(r, i);
            const float2 vA = hb2[(size_t)((rA >> 6) & 0x1FFFFu) * 64 + lane];
            const float2 cA = comp2[rA & 63u];
            atomicAdd(&acc[((rA >> 23) << 6) + lane], cA.x * vA.x + cA.y * vA.y);
        }
    }
    __syncthreads();

    // epilogue: out = act(self + acc), float4 lanes
    const float4* __restrict__ a4 = reinterpret_cast<const float4*>(acc);
    float4* __restrict__ io4 = reinterpret_cast<float4*>(io) + (size_t)n0 * 16;
    for (int i = threadIdx.x; i < 128 * 16; i += 512) {
        const int n = n0 + (i >> 4);
        if (n < nNodes) {
            float4 o = io4[i];
            const float4 a = a4[i];
            o.x += a.x; o.y += a.y; o.z += a.z; o.w += a.w;
            if (ACT == 0) {
                o.x = tanhf(o.x); o.y = tanhf(o.y);
                o.z = tanhf(o.z); o.w = tanhf(o.w);
            } else {
                o.x = fmaxf(o.x, 0.f); o.y = fmaxf(o.y, 0.f);
                o.z = fmaxf(o.z, 0.f); o.w = fmaxf(o.w, 0.f);
            }
            io4[i] = o;
        }
    }
}

// ---------------------------------------------------------------------------
extern "C" void kernel_launch(void* const* d_in, const int* in_sizes, int n_in,
                              void* d_out, int out_size, void* d_ws, size_t ws_size,
                              hipStream_t stream)
{
    const float* node_emb = (const float*)d_in[0];   // [N][128]
    const float* basis1   = (const float*)d_in[1];   // [2][128][64]
    const float* comp1    = (const float*)d_in[2];   // [R][2]
    const float* loop_w1  = (const float*)d_in[3];   // [128][64]
    const float* bias1    = (const float*)d_in[4];   // [64]
    const float* basis2   = (const float*)d_in[5];   // [2][64][64]
    const float* comp2    = (const float*)d_in[6];   // [R][2]
    const float* loop_w2  = (const float*)d_in[7];   // [64][64]
    const float* bias2    = (const float*)d_in[8];   // [64]
    const int*   src      = (const int*)d_in[9];     // [E]
    const int*   dst      = (const int*)d_in[10];    // [E]
    const int*   et       = (const int*)d_in[11];    // [E]

    const int N = in_sizes[0] / 128;
    const int E = in_sizes[9];
    const int nB = (N + 127) / 128;                  // dst buckets

    float* out = (float*)d_out;                      // [N][64]

    // workspace layout
    float*    hb     = (float*)d_ws;                 // N*128 f (float2 [N][64])
    float*    h      = hb + (size_t)N * 128;         // N*64 f
    unsigned* rec    = (unsigned*)(h + (size_t)N * 64); // E u32
    int*      hist   = (int*)(rec + E);              // nB
    int*      boff   = hist + nB;                    // nB+1
    int*      cursor = boff + nB + 1;                // nB
    u16*      wt1h   = (u16*)(cursor + nB);          // 192*128
    u16*      wt1l   = wt1h + 192 * 128;
    u16*      wt2h   = wt1l + 192 * 128;             // 192*64
    u16*      wt2l   = wt2h + 192 * 64;

    const int nBlkDense = (N + 127) / 128;
    const int nBlkE     = (E + 255) / 256;

    // ---- W pre-convert (bf16 hi/lo, transposed) ----
    wconv<<<96, 256, 0, stream>>>(loop_w1, basis1, loop_w2, basis2,
                                  wt1h, wt1l, wt2h, wt2l);

    // ---- bucket build (shared by both layers) ----
    hipMemsetAsync(hist, 0, (size_t)nB * sizeof(int), stream);
    bkt_hist   <<<nBlkE, 256, 0, stream>>>(dst, hist, E);
    bkt_scan   <<<1,    1024, 0, stream>>>(hist, boff, cursor, nB, E);
    bkt_scatter<<<nBlkE, 256, 0, stream>>>(src, dst, et, cursor, rec, E);

    // ---- layer 1 ----
    rgcn_dense_mfma<128><<<nBlkDense, 512, 0, stream>>>(
        node_emb, wt1h, wt1l, bias1, h, (float2*)hb, N);
    rgcn_agg<0><<<nB, 512, 0, stream>>>(
        (const float2*)hb, comp1, boff, rec, h, N);

    // ---- layer 2 ----
    rgcn_dense_mfma<64><<<nBlkDense, 512, 0, stream>>>(
        h, wt2h, wt2l, bias2, out, (float2*)hb, N);
    rgcn_agg<1><<<nB, 512, 0, stream>>>(
        (const float2*)hb, comp2, boff, rec, out, N);
}

// Round 9
// 714.607 us; speedup vs baseline: 1.9984x; 1.9984x over previous
//
#include <hip/hip_runtime.h>
#include <math.h>

// ---------------------------------------------------------------------------
// R-GCN (basis decomposition, B=2), 2 layers.
//   C[n, 0:192] = x[n,:] @ [loop_w | basis0 | basis1]   (dense, MFMA bf16x3)
//   self = C[:,0:64]+bias ;  hb2[n][j] = (C[n,64+j], C[n,128+j])  (float2)
//   out[n] = act(self[n] + sum_{e: dst=n} c0*hb2[src][j].x + c1*hb2[src][j].y)
//
// Dense via matrix cores with fp32 emulation: x = xh + xl, w = wh + wl
// (bf16 hi/lo, RNE); C = xh*wh + xh*wl + xl*wh  (xl*wl ~ 2^-18, dropped).
//
// Edge records grouped to per-node CSR in two cheap steps (no random 4B
// global scatter): (1) scatter into 128-node bucket regions (5KB windows,
// lines fill before eviction), (2) per-bucket LDS counting sort by node,
// emitting rowptr. Aggregation: one wave per node (100k waves), register
// accumulation, 8-deep gather unroll on interleaved float2 hb2.
// ---------------------------------------------------------------------------

typedef short          short8 __attribute__((ext_vector_type(8)));
typedef float          f32x4  __attribute__((ext_vector_type(4)));
typedef unsigned short u16;

static __device__ __forceinline__ u16 bf16_rne(float x) {
    unsigned u = __float_as_uint(x);
    return (u16)((u + 0x7fffu + ((u >> 16) & 1u)) >> 16);
}
static __device__ __forceinline__ float bf16_f32(u16 h) {
    return __uint_as_float(((unsigned)h) << 16);
}

// ---------------- W pre-convert: Wt[192][K] bf16 hi/lo (transposed) --------
__global__ __launch_bounds__(256) void wconv(
    const float* __restrict__ loopw1, const float* __restrict__ basis1,
    const float* __restrict__ loopw2, const float* __restrict__ basis2,
    u16* __restrict__ wt1h, u16* __restrict__ wt1l,
    u16* __restrict__ wt2h, u16* __restrict__ wt2l)
{
    const int tid = blockIdx.x * 256 + threadIdx.x;
    if (tid < 192 * 128) {                       // layer 1, K=128
        const int j = tid >> 7, k = tid & 127;
        const float w = (j < 64)
            ? loopw1[k * 64 + j]
            : basis1[(size_t)((j - 64) >> 6) * (128 * 64) + k * 64 + ((j - 64) & 63)];
        const u16 h = bf16_rne(w);
        wt1h[tid] = h;
        wt1l[tid] = bf16_rne(w - bf16_f32(h));
    }
    if (tid < 192 * 64) {                        // layer 2, K=64
        const int j = tid >> 6, k = tid & 63;
        const float w = (j < 64)
            ? loopw2[k * 64 + j]
            : basis2[(size_t)((j - 64) >> 6) * (64 * 64) + k * 64 + ((j - 64) & 63)];
        const u16 h = bf16_rne(w);
        wt2h[tid] = h;
        wt2l[tid] = bf16_rne(w - bf16_f32(h));
    }
}

// ---------------- dense: 128 nodes/block, 8 waves, W in LDS ----------------
template<int K>
__global__ __launch_bounds__(512, 2) void rgcn_dense_mfma(
    const float* __restrict__ x,     // [N][K] f32
    const u16* __restrict__ wth,     // [192][K] bf16 hi (transposed)
    const u16* __restrict__ wtl,     // [192][K] bf16 lo
    const float* __restrict__ bias,  // [64]
    float* __restrict__ self,        // [N][64]  = x@loopw + bias
    float2* __restrict__ hb2,        // [N][64]  = (x@basis0, x@basis1) pairs
    int nNodes)
{
    constexpr int KC  = K / 32;          // mfma K-steps
    constexpr int GW  = K / 8;           // 16B granules per (col,split)
    constexpr int GMW = GW - 1;          // granule XOR mask
    __shared__ u16 wlds[96 * 2 * K];     // one 96-col half of W (hi+lo)

    const int n0   = blockIdx.x * 128;
    const int lane = threadIdx.x & 63;
    const int w    = threadIdx.x >> 6;   // 0..7
    const int rl   = lane & 15;          // A row / B col / D col
    const int kb   = lane >> 4;          // k-block

    // ---- A fragments: global -> reg, convert to bf16 hi/lo ----
    const int row = n0 + w * 16 + rl;
    short8 Ah[KC], Al[KC];
    #pragma unroll
    for (int kc = 0; kc < KC; ++kc) {
        float v[8];
        if (row < nNodes) {
            const float* xp = x + (size_t)row * K + kc * 32 + kb * 8;
            const float4 a = *reinterpret_cast<const float4*>(xp);
            const float4 b = *reinterpret_cast<const float4*>(xp + 4);
            v[0] = a.x; v[1] = a.y; v[2] = a.z; v[3] = a.w;
            v[4] = b.x; v[5] = b.y; v[6] = b.z; v[7] = b.w;
        } else {
            #pragma unroll
            for (int i = 0; i < 8; ++i) v[i] = 0.f;
        }
        #pragma unroll
        for (int i = 0; i < 8; ++i) {
            const u16 h = bf16_rne(v[i]);
            Ah[kc][i] = (short)h;
            Al[kc][i] = (short)bf16_rne(v[i] - bf16_f32(h));
        }
    }

    f32x4 acc[12];
    #pragma unroll
    for (int j = 0; j < 12; ++j) acc[j] = (f32x4){0.f, 0.f, 0.f, 0.f};

    #pragma unroll
    for (int hf = 0; hf < 2; ++hf) {
        if (hf) __syncthreads();         // protect LDS before overwrite
        // ---- stage 96 cols of W (hi+lo) into LDS, XOR-swizzled ----
        for (int gi = threadIdx.x; gi < 96 * 2 * GW; gi += 512) {
            const int ch = gi / (2 * GW);
            const int r  = gi - ch * 2 * GW;
            const int s  = r / GW;
            const int g  = r - s * GW;
            const u16* sp = (s == 0 ? wth : wtl)
                          + (size_t)(hf * 96 + ch) * K + g * 8;
            const short8 vv = *reinterpret_cast<const short8*>(sp);
            *reinterpret_cast<short8*>(
                &wlds[((ch * 2 + s) * GW + (g ^ (ch & GMW))) * 8]) = vv;
        }
        __syncthreads();

        #pragma unroll
        for (int j16h = 0; j16h < 6; ++j16h) {
            const int ch = j16h * 16 + rl;
            const u16* bbase = &wlds[(ch * 2) * GW * 8];
            #pragma unroll
            for (int kc = 0; kc < KC; ++kc) {
                const int gp = (kc * 4 + kb) ^ (ch & GMW);
                const short8 Bh =
                    *reinterpret_cast<const short8*>(bbase + gp * 8);
                const short8 Bl =
                    *reinterpret_cast<const short8*>(bbase + (GW + gp) * 8);
                f32x4 a = acc[hf * 6 + j16h];
                a = __builtin_amdgcn_mfma_f32_16x16x32_bf16(Ah[kc], Bh, a, 0, 0, 0);
                a = __builtin_amdgcn_mfma_f32_16x16x32_bf16(Ah[kc], Bl, a, 0, 0, 0);
                a = __builtin_amdgcn_mfma_f32_16x16x32_bf16(Al[kc], Bh, a, 0, 0, 0);
                acc[hf * 6 + j16h] = a;
            }
        }
    }

    // ---- epilogue: D[(kb*4+r)][rl] ----
    const int rowbase = n0 + w * 16 + kb * 4;
    #pragma unroll
    for (int j16 = 0; j16 < 4; ++j16) {          // cols 0..63 -> self + bias
        const float bj = bias[j16 * 16 + rl];
        #pragma unroll
        for (int r = 0; r < 4; ++r) {
            const int rr = rowbase + r;
            if (rr < nNodes)
                self[(size_t)rr * 64 + j16 * 16 + rl] = acc[j16][r] + bj;
        }
    }
    #pragma unroll
    for (int j16 = 4; j16 < 8; ++j16) {          // (basis0, basis1) pairs
        #pragma unroll
        for (int r = 0; r < 4; ++r) {
            const int rr = rowbase + r;
            if (rr < nNodes)
                hb2[(size_t)rr * 64 + (j16 - 4) * 16 + rl] =
                    make_float2(acc[j16][r], acc[j16 + 4][r]);
        }
    }
}

// ---------------- bucket build -------------------------------------------
__global__ __launch_bounds__(256) void bkt_hist(
    const int* __restrict__ dst, int* __restrict__ hist, int nE)
{
    const int e = blockIdx.x * 256 + threadIdx.x;
    if (e < nE) atomicAdd(&hist[dst[e] >> 7], 1);
}

__global__ __launch_bounds__(1024) void bkt_scan(
    const int* __restrict__ hist, int* __restrict__ boff,
    int* __restrict__ cursor, int nB, int nE)
{
    __shared__ int sm[1024];
    const int t = threadIdx.x;
    const int v = (t < nB) ? hist[t] : 0;
    sm[t] = v; __syncthreads();
    for (int off = 1; off < 1024; off <<= 1) {
        const int u = (t >= off) ? sm[t - off] : 0;
        __syncthreads();
        sm[t] += u;
        __syncthreads();
    }
    if (t < nB) {
        const int ex = sm[t] - v;      // exclusive
        boff[t] = ex;
        cursor[t] = ex;
    }
    if (t == 0) boff[nB] = nE;
}

// rec = dl(7)<<23 | src(17)<<6 | et(6); writes cluster in 5KB bucket windows
__global__ __launch_bounds__(256) void bkt_scatter(
    const int* __restrict__ src, const int* __restrict__ dst,
    const int* __restrict__ et, int* __restrict__ cursor,
    unsigned* __restrict__ rec, int nE)
{
    const int e = blockIdx.x * 256 + threadIdx.x;
    if (e < nE) {
        const int d = dst[e];
        const int p = atomicAdd(&cursor[d >> 7], 1);
        rec[p] = ((unsigned)(d & 127) << 23)
               | ((unsigned)src[e] << 6)
               | (unsigned)et[e];
    }
}

// ---------------- per-bucket counting sort by node; emits rowptr -----------
__global__ __launch_bounds__(256) void bkt_sort(
    const unsigned* __restrict__ rec, unsigned* __restrict__ rec2,
    const int* __restrict__ boff, int* __restrict__ rowptr,
    int nNodes)
{
    __shared__ int cnt[128];
    __shared__ int pos[128];
    const int b = blockIdx.x;
    const int t = threadIdx.x;
    const int beg = boff[b], end = boff[b + 1];
    if (t < 128) cnt[t] = 0;
    __syncthreads();
    for (int i = beg + t; i < end; i += 256)
        atomicAdd(&cnt[rec[i] >> 23], 1);
    __syncthreads();
    if (t < 128) pos[t] = cnt[t];
    __syncthreads();
    for (int off = 1; off < 128; off <<= 1) {     // Hillis-Steele inclusive
        int u = 0;
        if (t < 128 && t >= off) u = pos[t - off];
        __syncthreads();
        if (t < 128) pos[t] += u;
        __syncthreads();
    }
    if (t < 128) {
        const int ex = beg + pos[t] - cnt[t];     // exclusive + bucket base
        pos[t] = ex;
        const int n = (b << 7) + t;
        if (n < nNodes) rowptr[n] = ex;
    }
    __syncthreads();
    for (int i = beg + t; i < end; i += 256) {
        const unsigned r = rec[i];
        const int p = atomicAdd(&pos[r >> 23], 1);
        rec2[p] = r;                               // 5KB window write
    }
}

// ---------------- edge aggregation: one wave per dst node ------------------
template<int ACT>   // 0 = tanh, 1 = relu
__global__ __launch_bounds__(256) void rgcn_agg(
    const float2* __restrict__ hb2,     // [N][64] float2 (b0,b1)
    const float* __restrict__ comp,     // [R][2]
    const int* __restrict__ rowptr,     // [N], node-sorted rec2 offsets
    const unsigned* __restrict__ rec2,  // [E] node-grouped
    float* __restrict__ io,             // in: self+bias, out: act(self+agg)
    int nNodes, int nEdges)
{
    const int lane = threadIdx.x & 63;
    const int w  = (blockIdx.x * 256 + threadIdx.x) >> 6;
    const int nW = (gridDim.x * 256) >> 6;
    const float2* __restrict__ comp2 = reinterpret_cast<const float2*>(comp);
    for (int n = w; n < nNodes; n += nW) {
        const int beg = rowptr[n];
        const int end = (n == nNodes - 1) ? nEdges : rowptr[n + 1];
        const float self = io[(size_t)n * 64 + lane];   // issue early
        float acc0 = 0.f, acc1 = 0.f;
        for (int base = beg; base < end; base += 64) {
            const int cnt = min(64, end - base);
            const unsigned r = (lane < cnt) ? rec2[base + lane] : 0u;
            int i = 0;
            for (; i + 8 <= cnt; i += 8) {
                unsigned rr[8];
                #pragma unroll
                for (int k = 0; k < 8; ++k) rr[k] = __shfl(r, i + k);
                float2 v[8];
                #pragma unroll
                for (int k = 0; k < 8; ++k)
                    v[k] = hb2[(size_t)((rr[k] >> 6) & 0x1FFFFu) * 64 + lane];
                #pragma unroll
                for (int k = 0; k < 8; ++k) {
                    const float2 c = comp2[rr[k] & 63u];
                    acc0 = fmaf(c.x, v[k].x, acc0);
                    acc1 = fmaf(c.y, v[k].y, acc1);
                }
            }
            for (; i < cnt; ++i) {
                const unsigned rA = __shfl(r, i);
                const float2 vA = hb2[(size_t)((rA >> 6) & 0x1FFFFu) * 64 + lane];
                const float2 c = comp2[rA & 63u];
                acc0 = fmaf(c.x, vA.x, acc0);
                acc1 = fmaf(c.y, vA.y, acc1);
            }
        }
        float o = self + acc0 + acc1;
        o = (ACT == 0) ? tanhf(o) : fmaxf(o, 0.f);
        io[(size_t)n * 64 + lane] = o;
    }
}

// ---------------------------------------------------------------------------
extern "C" void kernel_launch(void* const* d_in, const int* in_sizes, int n_in,
                              void* d_out, int out_size, void* d_ws, size_t ws_size,
                              hipStream_t stream)
{
    const float* node_emb = (const float*)d_in[0];   // [N][128]
    const float* basis1   = (const float*)d_in[1];   // [2][128][64]
    const float* comp1    = (const float*)d_in[2];   // [R][2]
    const float* loop_w1  = (const float*)d_in[3];   // [128][64]
    const float* bias1    = (const float*)d_in[4];   // [64]
    const float* basis2   = (const float*)d_in[5];   // [2][64][64]
    const float* comp2    = (const float*)d_in[6];   // [R][2]
    const float* loop_w2  = (const float*)d_in[7];   // [64][64]
    const float* bias2    = (const float*)d_in[8];   // [64]
    const int*   src      = (const int*)d_in[9];     // [E]
    const int*   dst      = (const int*)d_in[10];    // [E]
    const int*   et       = (const int*)d_in[11];    // [E]

    const int N = in_sizes[0] / 128;
    const int E = in_sizes[9];
    const int nB = (N + 127) / 128;                  // dst buckets

    float* out = (float*)d_out;                      // [N][64]

    // workspace layout
    float*    hb     = (float*)d_ws;                 // N*128 f (float2 [N][64])
    float*    h      = hb + (size_t)N * 128;         // N*64 f
    unsigned* rec    = (unsigned*)(h + (size_t)N * 64); // E u32 (bucket-grouped)
    unsigned* rec2   = rec + E;                      // E u32 (node-grouped)
    int*      hist   = (int*)(rec2 + E);             // nB
    int*      boff   = hist + nB;                    // nB+1
    int*      cursor = boff + nB + 1;                // nB
    int*      rowptr = cursor + nB;                  // N
    u16*      wt1h   = (u16*)(rowptr + N);           // 192*128
    u16*      wt1l   = wt1h + 192 * 128;
    u16*      wt2h   = wt1l + 192 * 128;             // 192*64
    u16*      wt2l   = wt2h + 192 * 64;

    const int nBlkDense = (N + 127) / 128;
    const int nBlkE     = (E + 255) / 256;
    const int nBlkAgg   = (N + 3) / 4;               // 1 wave per node

    // ---- W pre-convert (bf16 hi/lo, transposed) ----
    wconv<<<96, 256, 0, stream>>>(loop_w1, basis1, loop_w2, basis2,
                                  wt1h, wt1l, wt2h, wt2l);

    // ---- per-node CSR via bucket scatter + per-bucket counting sort ----
    hipMemsetAsync(hist, 0, (size_t)nB * sizeof(int), stream);
    bkt_hist   <<<nBlkE, 256, 0, stream>>>(dst, hist, E);
    bkt_scan   <<<1,    1024, 0, stream>>>(hist, boff, cursor, nB, E);
    bkt_scatter<<<nBlkE, 256, 0, stream>>>(src, dst, et, cursor, rec, E);
    bkt_sort   <<<nB,    256, 0, stream>>>(rec, rec2, boff, rowptr, N);

    // ---- layer 1 ----
    rgcn_dense_mfma<128><<<nBlkDense, 512, 0, stream>>>(
        node_emb, wt1h, wt1l, bias1, h, (float2*)hb, N);
    rgcn_agg<0><<<nBlkAgg, 256, 0, stream>>>(
        (const float2*)hb, comp1, rowptr, rec2, h, N, E);

    // ---- layer 2 ----
    rgcn_dense_mfma<64><<<nBlkDense, 512, 0, stream>>>(
        h, wt2h, wt2l, bias2, out, (float2*)hb, N);
    rgcn_agg<1><<<nBlkAgg, 256, 0, stream>>>(
        (const float2*)hb, comp2, rowptr, rec2, out, N, E);
}

// Round 10
// 287.078 us; speedup vs baseline: 4.9744x; 2.4892x over previous
//
#include <hip/hip_runtime.h>
#include <math.h>

// ---------------------------------------------------------------------------
// R-GCN (basis decomposition, B=2), 2 layers.
//   C[n, 0:192] = x[n,:] @ [loop_w | basis0 | basis1]   (dense, MFMA bf16x3)
//   self = C[:,0:64]+bias ;  hb2[n][j] = (C[n,64+j], C[n,128+j])  (float2)
//   out[n] = act(self[n] + sum_{e: dst=n} c0*hb2[src][j].x + c1*hb2[src][j].y)
//
// Dense via matrix cores with fp32 emulation: x = xh + xl, w = wh + wl
// (bf16 hi/lo, RNE); C = xh*wh + xh*wl + xl*wh  (xl*wl ~ 2^-18, dropped).
//
// CSR build with NO hot-line atomics (round-9 lesson: 1M fetch-adds on 49
// cache lines = 236us):
//   1) chunk blocks histogram edges into a 782-counter LDS hist, flush to
//      64B-PADDED global counters (200k atomics over 782 lines)
//   2) single-block scan -> bucket offsets + padded cursors
//   3) chunk blocks claim one contiguous range per (block,bucket) with ONE
//      padded atomic-return, then place records via LDS cursors
//   4) per-bucket LDS counting sort -> node-grouped rec2 + per-node rowptr
// Aggregation: one wave per node (100k waves), register acc, 8-deep gathers.
// ---------------------------------------------------------------------------

typedef short          short8 __attribute__((ext_vector_type(8)));
typedef float          f32x4  __attribute__((ext_vector_type(4)));
typedef unsigned short u16;

#define CPAD 16          // ints per padded counter (64B line)
#define NCHUNK 256       // chunk blocks for hist/scatter

static __device__ __forceinline__ u16 bf16_rne(float x) {
    unsigned u = __float_as_uint(x);
    return (u16)((u + 0x7fffu + ((u >> 16) & 1u)) >> 16);
}
static __device__ __forceinline__ float bf16_f32(u16 h) {
    return __uint_as_float(((unsigned)h) << 16);
}

// ---------------- W pre-convert: Wt[192][K] bf16 hi/lo (transposed) --------
__global__ __launch_bounds__(256) void wconv(
    const float* __restrict__ loopw1, const float* __restrict__ basis1,
    const float* __restrict__ loopw2, const float* __restrict__ basis2,
    u16* __restrict__ wt1h, u16* __restrict__ wt1l,
    u16* __restrict__ wt2h, u16* __restrict__ wt2l)
{
    const int tid = blockIdx.x * 256 + threadIdx.x;
    if (tid < 192 * 128) {                       // layer 1, K=128
        const int j = tid >> 7, k = tid & 127;
        const float w = (j < 64)
            ? loopw1[k * 64 + j]
            : basis1[(size_t)((j - 64) >> 6) * (128 * 64) + k * 64 + ((j - 64) & 63)];
        const u16 h = bf16_rne(w);
        wt1h[tid] = h;
        wt1l[tid] = bf16_rne(w - bf16_f32(h));
    }
    if (tid < 192 * 64) {                        // layer 2, K=64
        const int j = tid >> 6, k = tid & 63;
        const float w = (j < 64)
            ? loopw2[k * 64 + j]
            : basis2[(size_t)((j - 64) >> 6) * (64 * 64) + k * 64 + ((j - 64) & 63)];
        const u16 h = bf16_rne(w);
        wt2h[tid] = h;
        wt2l[tid] = bf16_rne(w - bf16_f32(h));
    }
}

// ---------------- dense: 128 nodes/block, 8 waves, W in LDS ----------------
template<int K>
__global__ __launch_bounds__(512, 2) void rgcn_dense_mfma(
    const float* __restrict__ x,     // [N][K] f32
    const u16* __restrict__ wth,     // [192][K] bf16 hi (transposed)
    const u16* __restrict__ wtl,     // [192][K] bf16 lo
    const float* __restrict__ bias,  // [64]
    float* __restrict__ self,        // [N][64]  = x@loopw + bias
    float2* __restrict__ hb2,        // [N][64]  = (x@basis0, x@basis1) pairs
    int nNodes)
{
    constexpr int KC  = K / 32;          // mfma K-steps
    constexpr int GW  = K / 8;           // 16B granules per (col,split)
    constexpr int GMW = GW - 1;          // granule XOR mask
    __shared__ u16 wlds[96 * 2 * K];     // one 96-col half of W (hi+lo)

    const int n0   = blockIdx.x * 128;
    const int lane = threadIdx.x & 63;
    const int w    = threadIdx.x >> 6;   // 0..7
    const int rl   = lane & 15;          // A row / B col / D col
    const int kb   = lane >> 4;          // k-block

    // ---- A fragments: global -> reg, convert to bf16 hi/lo ----
    const int row = n0 + w * 16 + rl;
    short8 Ah[KC], Al[KC];
    #pragma unroll
    for (int kc = 0; kc < KC; ++kc) {
        float v[8];
        if (row < nNodes) {
            const float* xp = x + (size_t)row * K + kc * 32 + kb * 8;
            const float4 a = *reinterpret_cast<const float4*>(xp);
            const float4 b = *reinterpret_cast<const float4*>(xp + 4);
            v[0] = a.x; v[1] = a.y; v[2] = a.z; v[3] = a.w;
            v[4] = b.x; v[5] = b.y; v[6] = b.z; v[7] = b.w;
        } else {
            #pragma unroll
            for (int i = 0; i < 8; ++i) v[i] = 0.f;
        }
        #pragma unroll
        for (int i = 0; i < 8; ++i) {
            const u16 h = bf16_rne(v[i]);
            Ah[kc][i] = (short)h;
            Al[kc][i] = (short)bf16_rne(v[i] - bf16_f32(h));
        }
    }

    f32x4 acc[12];
    #pragma unroll
    for (int j = 0; j < 12; ++j) acc[j] = (f32x4){0.f, 0.f, 0.f, 0.f};

    #pragma unroll
    for (int hf = 0; hf < 2; ++hf) {
        if (hf) __syncthreads();         // protect LDS before overwrite
        // ---- stage 96 cols of W (hi+lo) into LDS, XOR-swizzled ----
        for (int gi = threadIdx.x; gi < 96 * 2 * GW; gi += 512) {
            const int ch = gi / (2 * GW);
            const int r  = gi - ch * 2 * GW;
            const int s  = r / GW;
            const int g  = r - s * GW;
            const u16* sp = (s == 0 ? wth : wtl)
                          + (size_t)(hf * 96 + ch) * K + g * 8;
            const short8 vv = *reinterpret_cast<const short8*>(sp);
            *reinterpret_cast<short8*>(
                &wlds[((ch * 2 + s) * GW + (g ^ (ch & GMW))) * 8]) = vv;
        }
        __syncthreads();

        #pragma unroll
        for (int j16h = 0; j16h < 6; ++j16h) {
            const int ch = j16h * 16 + rl;
            const u16* bbase = &wlds[(ch * 2) * GW * 8];
            #pragma unroll
            for (int kc = 0; kc < KC; ++kc) {
                const int gp = (kc * 4 + kb) ^ (ch & GMW);
                const short8 Bh =
                    *reinterpret_cast<const short8*>(bbase + gp * 8);
                const short8 Bl =
                    *reinterpret_cast<const short8*>(bbase + (GW + gp) * 8);
                f32x4 a = acc[hf * 6 + j16h];
                a = __builtin_amdgcn_mfma_f32_16x16x32_bf16(Ah[kc], Bh, a, 0, 0, 0);
                a = __builtin_amdgcn_mfma_f32_16x16x32_bf16(Ah[kc], Bl, a, 0, 0, 0);
                a = __builtin_amdgcn_mfma_f32_16x16x32_bf16(Al[kc], Bh, a, 0, 0, 0);
                acc[hf * 6 + j16h] = a;
            }
        }
    }

    // ---- epilogue: D[(kb*4+r)][rl] ----
    const int rowbase = n0 + w * 16 + kb * 4;
    #pragma unroll
    for (int j16 = 0; j16 < 4; ++j16) {          // cols 0..63 -> self + bias
        const float bj = bias[j16 * 16 + rl];
        #pragma unroll
        for (int r = 0; r < 4; ++r) {
            const int rr = rowbase + r;
            if (rr < nNodes)
                self[(size_t)rr * 64 + j16 * 16 + rl] = acc[j16][r] + bj;
        }
    }
    #pragma unroll
    for (int j16 = 4; j16 < 8; ++j16) {          // (basis0, basis1) pairs
        #pragma unroll
        for (int r = 0; r < 4; ++r) {
            const int rr = rowbase + r;
            if (rr < nNodes)
                hb2[(size_t)rr * 64 + (j16 - 4) * 16 + rl] =
                    make_float2(acc[j16][r], acc[j16 + 4][r]);
        }
    }
}

// ---------------- bucket build: LDS-aggregated, padded counters ------------
// block p owns edges [p*chunk, min(E,(p+1)*chunk))
__global__ __launch_bounds__(256) void bkt_hist(
    const int* __restrict__ dst, int* __restrict__ histp, int nE, int nB)
{
    __shared__ int lh[1024];
    const int t = threadIdx.x;
    for (int b = t; b < nB; b += 256) lh[b] = 0;
    __syncthreads();
    const int chunk = (nE + NCHUNK - 1) / NCHUNK;
    const int e0 = blockIdx.x * chunk;
    const int e1 = min(nE, e0 + chunk);
    for (int e = e0 + t; e < e1; e += 256)
        atomicAdd(&lh[dst[e] >> 7], 1);
    __syncthreads();
    for (int b = t; b < nB; b += 256)
        if (lh[b]) atomicAdd(&histp[b * CPAD], lh[b]);
}

__global__ __launch_bounds__(1024) void bkt_scan(
    const int* __restrict__ histp, int* __restrict__ boff,
    int* __restrict__ cursorp, int nB, int nE)
{
    __shared__ int sm[1024];
    const int t = threadIdx.x;
    const int v = (t < nB) ? histp[t * CPAD] : 0;
    sm[t] = v; __syncthreads();
    for (int off = 1; off < 1024; off <<= 1) {
        const int u = (t >= off) ? sm[t - off] : 0;
        __syncthreads();
        sm[t] += u;
        __syncthreads();
    }
    if (t < nB) {
        const int ex = sm[t] - v;      // exclusive
        boff[t] = ex;
        cursorp[t * CPAD] = ex;
    }
    if (t == 0) boff[nB] = nE;
}

// rec = dl(7)<<23 | src(17)<<6 | et(6)
__global__ __launch_bounds__(256) void bkt_scatter(
    const int* __restrict__ src, const int* __restrict__ dst,
    const int* __restrict__ et, int* __restrict__ cursorp,
    unsigned* __restrict__ rec, int nE, int nB)
{
    __shared__ int lh[1024];
    const int t = threadIdx.x;
    for (int b = t; b < nB; b += 256) lh[b] = 0;
    __syncthreads();
    const int chunk = (nE + NCHUNK - 1) / NCHUNK;
    const int e0 = blockIdx.x * chunk;
    const int e1 = min(nE, e0 + chunk);
    // pass 1: local counts
    for (int e = e0 + t; e < e1; e += 256)
        atomicAdd(&lh[dst[e] >> 7], 1);
    __syncthreads();
    // pass 2: claim one contiguous range per touched bucket
    for (int b = t; b < nB; b += 256) {
        const int c = lh[b];
        lh[b] = c ? atomicAdd(&cursorp[b * CPAD], c) : 0;
    }
    __syncthreads();
    // pass 3: place records via LDS cursors
    for (int e = e0 + t; e < e1; e += 256) {
        const int d = dst[e];
        const int p = atomicAdd(&lh[d >> 7], 1);
        rec[p] = ((unsigned)(d & 127) << 23)
               | ((unsigned)src[e] << 6)
               | (unsigned)et[e];
    }
}

// ---------------- per-bucket counting sort by node; emits rowptr -----------
__global__ __launch_bounds__(256) void bkt_sort(
    const unsigned* __restrict__ rec, unsigned* __restrict__ rec2,
    const int* __restrict__ boff, int* __restrict__ rowptr,
    int nNodes)
{
    __shared__ int cnt[128];
    __shared__ int pos[128];
    const int b = blockIdx.x;
    const int t = threadIdx.x;
    const int beg = boff[b], end = boff[b + 1];
    if (t < 128) cnt[t] = 0;
    __syncthreads();
    for (int i = beg + t; i < end; i += 256)
        atomicAdd(&cnt[rec[i] >> 23], 1);
    __syncthreads();
    if (t < 128) pos[t] = cnt[t];
    __syncthreads();
    for (int off = 1; off < 128; off <<= 1) {     // Hillis-Steele inclusive
        int u = 0;
        if (t < 128 && t >= off) u = pos[t - off];
        __syncthreads();
        if (t < 128) pos[t] += u;
        __syncthreads();
    }
    if (t < 128) {
        const int ex = beg + pos[t] - cnt[t];     // exclusive + bucket base
        pos[t] = ex;
        const int n = (b << 7) + t;
        if (n < nNodes) rowptr[n] = ex;
    }
    __syncthreads();
    for (int i = beg + t; i < end; i += 256) {
        const unsigned r = rec[i];
        const int p = atomicAdd(&pos[r >> 23], 1);
        rec2[p] = r;                               // bucket-window write
    }
}

// ---------------- edge aggregation: one wave per dst node ------------------
template<int ACT>   // 0 = tanh, 1 = relu
__global__ __launch_bounds__(256) void rgcn_agg(
    const float2* __restrict__ hb2,     // [N][64] float2 (b0,b1)
    const float* __restrict__ comp,     // [R][2]
    const int* __restrict__ rowptr,     // [N], node-sorted rec2 offsets
    const unsigned* __restrict__ rec2,  // [E] node-grouped
    float* __restrict__ io,             // in: self+bias, out: act(self+agg)
    int nNodes, int nEdges)
{
    const int lane = threadIdx.x & 63;
    const int w  = (blockIdx.x * 256 + threadIdx.x) >> 6;
    const int nW = (gridDim.x * 256) >> 6;
    const float2* __restrict__ comp2 = reinterpret_cast<const float2*>(comp);
    for (int n = w; n < nNodes; n += nW) {
        const int beg = rowptr[n];
        const int end = (n == nNodes - 1) ? nEdges : rowptr[n + 1];
        const float self = io[(size_t)n * 64 + lane];   // issue early
        float acc0 = 0.f, acc1 = 0.f;
        for (int base = beg; base < end; base += 64) {
            const int cnt = min(64, end - base);
            const unsigned r = (lane < cnt) ? rec2[base + lane] : 0u;
            int i = 0;
            for (; i + 8 <= cnt; i += 8) {
                unsigned rr[8];
                #pragma unroll
                for (int k = 0; k < 8; ++k) rr[k] = __shfl(r, i + k);
                float2 v[8];
                #pragma unroll
                for (int k = 0; k < 8; ++k)
                    v[k] = hb2[(size_t)((rr[k] >> 6) & 0x1FFFFu) * 64 + lane];
                #pragma unroll
                for (int k = 0; k < 8; ++k) {
                    const float2 c = comp2[rr[k] & 63u];
                    acc0 = fmaf(c.x, v[k].x, acc0);
                    acc1 = fmaf(c.y, v[k].y, acc1);
                }
            }
            for (; i < cnt; ++i) {
                const unsigned rA = __shfl(r, i);
                const float2 vA = hb2[(size_t)((rA >> 6) & 0x1FFFFu) * 64 + lane];
                const float2 c = comp2[rA & 63u];
                acc0 = fmaf(c.x, vA.x, acc0);
                acc1 = fmaf(c.y, vA.y, acc1);
            }
        }
        float o = self + acc0 + acc1;
        o = (ACT == 0) ? tanhf(o) : fmaxf(o, 0.f);
        io[(size_t)n * 64 + lane] = o;
    }
}

// ---------------------------------------------------------------------------
extern "C" void kernel_launch(void* const* d_in, const int* in_sizes, int n_in,
                              void* d_out, int out_size, void* d_ws, size_t ws_size,
                              hipStream_t stream)
{
    const float* node_emb = (const float*)d_in[0];   // [N][128]
    const float* basis1   = (const float*)d_in[1];   // [2][128][64]
    const float* comp1    = (const float*)d_in[2];   // [R][2]
    const float* loop_w1  = (const float*)d_in[3];   // [128][64]
    const float* bias1    = (const float*)d_in[4];   // [64]
    const float* basis2   = (const float*)d_in[5];   // [2][64][64]
    const float* comp2    = (const float*)d_in[6];   // [R][2]
    const float* loop_w2  = (const float*)d_in[7];   // [64][64]
    const float* bias2    = (const float*)d_in[8];   // [64]
    const int*   src      = (const int*)d_in[9];     // [E]
    const int*   dst      = (const int*)d_in[10];    // [E]
    const int*   et       = (const int*)d_in[11];    // [E]

    const int N = in_sizes[0] / 128;
    const int E = in_sizes[9];
    const int nB = (N + 127) / 128;                  // dst buckets (<=1024)

    float* out = (float*)d_out;                      // [N][64]

    // workspace layout
    float*    hb      = (float*)d_ws;                // N*128 f (float2 [N][64])
    float*    h       = hb + (size_t)N * 128;        // N*64 f
    unsigned* rec     = (unsigned*)(h + (size_t)N * 64); // E u32 (bucket-grouped)
    unsigned* rec2    = rec + E;                     // E u32 (node-grouped)
    int*      histp   = (int*)(rec2 + E);            // nB*CPAD (padded)
    int*      cursorp = histp + nB * CPAD;           // nB*CPAD (padded)
    int*      boff    = cursorp + nB * CPAD;         // nB+1
    int*      rowptr  = boff + nB + 1;               // N
    u16*      wt1h    = (u16*)(rowptr + N);          // 192*128
    u16*      wt1l    = wt1h + 192 * 128;
    u16*      wt2h    = wt1l + 192 * 128;            // 192*64
    u16*      wt2l    = wt2h + 192 * 64;

    const int nBlkDense = (N + 127) / 128;
    const int nBlkAgg   = (N + 3) / 4;               // 1 wave per node

    // ---- W pre-convert (bf16 hi/lo, transposed) ----
    wconv<<<96, 256, 0, stream>>>(loop_w1, basis1, loop_w2, basis2,
                                  wt1h, wt1l, wt2h, wt2l);

    // ---- per-node CSR: LDS-agg hist -> scan -> range-claim scatter -> sort
    hipMemsetAsync(histp, 0, (size_t)nB * CPAD * sizeof(int), stream);
    bkt_hist   <<<NCHUNK, 256, 0, stream>>>(dst, histp, E, nB);
    bkt_scan   <<<1,     1024, 0, stream>>>(histp, boff, cursorp, nB, E);
    bkt_scatter<<<NCHUNK, 256, 0, stream>>>(src, dst, et, cursorp, rec, E, nB);
    bkt_sort   <<<nB,     256, 0, stream>>>(rec, rec2, boff, rowptr, N);

    // ---- layer 1 ----
    rgcn_dense_mfma<128><<<nBlkDense, 512, 0, stream>>>(
        node_emb, wt1h, wt1l, bias1, h, (float2*)hb, N);
    rgcn_agg<0><<<nBlkAgg, 256, 0, stream>>>(
        (const float2*)hb, comp1, rowptr, rec2, h, N, E);

    // ---- layer 2 ----
    rgcn_dense_mfma<64><<<nBlkDense, 512, 0, stream>>>(
        h, wt2h, wt2l, bias2, out, (float2*)hb, N);
    rgcn_agg<1><<<nBlkAgg, 256, 0, stream>>>(
        (const float2*)hb, comp2, rowptr, rec2, out, N, E);
}